// Round 10
// baseline (234.716 us; speedup 1.0000x reference)
//
#include <hip/hip_runtime.h>
#include <hip/hip_fp16.h>

#define IN_C 128
#define H 64
#define NBITS 9            // 512 nodes per bucket
#define BSZ 512
#define CAP 16384          // edge capacity per bucket (mean 8163, sigma ~90)
#define BINCHUNK 4096      // edges per bin block

typedef unsigned int u32;
typedef __attribute__((ext_vector_type(8))) _Float16 h8;
typedef __attribute__((ext_vector_type(4))) float f4;

// exclusive prefix sum of v across 256 threads; wsum = 4-int LDS scratch
__device__ __forceinline__ int excl_scan256(int v, int* wsum, int tid) {
    int lane = tid & 63, wid = tid >> 6;
    int s = v;
    #pragma unroll
    for (int off = 1; off < 64; off <<= 1) {
        int t = __shfl_up(s, off);
        if (lane >= off) s += t;
    }
    if (lane == 63) wsum[wid] = s;
    __syncthreads();
    if (tid == 0) {
        int c = 0;
        #pragma unroll
        for (int i = 0; i < 4; ++i) { int t = wsum[i]; wsum[i] = c; c += t; }
    }
    __syncthreads();
    return s - v + wsum[wid];
}

// exclusive prefix sum across 512 threads; wsum = 8-int LDS scratch
__device__ __forceinline__ int excl_scan512(int v, int* wsum, int tid) {
    int lane = tid & 63, wid = tid >> 6;
    int s = v;
    #pragma unroll
    for (int off = 1; off < 64; off <<= 1) {
        int t = __shfl_up(s, off);
        if (lane >= off) s += t;
    }
    if (lane == 63) wsum[wid] = s;
    __syncthreads();
    if (tid == 0) {
        int c = 0;
        #pragma unroll
        for (int i = 0; i < 8; ++i) { int t = wsum[i]; wsum[i] = c; c += t; }
    }
    __syncthreads();
    return s - v + wsum[wid];
}

// ---------------- init: zero bucketFill + pad rows + build fp16 transposed weights ----------------
__global__ __launch_bounds__(256) void k_init(int* __restrict__ bucketFill,
                                              __half* __restrict__ z0,
                                              __half* __restrict__ z1,
                                              const float* __restrict__ W1,
                                              const float* __restrict__ Wmu,
                                              const float* __restrict__ Wls,
                                              _Float16* __restrict__ W1T,
                                              _Float16* __restrict__ WT2) {
    int tid = threadIdx.x;
    int gt = blockIdx.x * 256 + tid;
    if (blockIdx.x == 0) {
        bucketFill[tid] = 0;
        if (tid < H) { z0[tid] = __float2half(0.f); z1[tid] = __float2half(0.f); }
    }
    for (int t = gt; t < 64 * 128; t += gridDim.x * 256) {
        int col = t >> 7, k = t & 127;
        W1T[t] = (_Float16)W1[k * 64 + col];
    }
    for (int t = gt; t < 64 * 64; t += gridDim.x * 256) {
        int col = t >> 6, k = t & 63;
        WT2[t] = (_Float16)((col < 32) ? Wmu[k * 32 + col] : Wls[k * 32 + (col - 32)]);
    }
}

// ---------------- mm1 tile (MFMA): Ah[node][c] = fp16( x[node][:] @ W1[:][c] ), UNSCALED
// All 8 x-loads (128 B/lane) issued up front.
__device__ __forceinline__ void mm1_tile_mfma(int tile, int t256, int n,
                                              const float* __restrict__ x,
                                              const _Float16* __restrict__ W1T,
                                              __half* __restrict__ out) {
    int wave = t256 >> 6, lane = t256 & 63;
    int cl = lane & 15;
    int kg = lane >> 4;
    int arow = tile * 64 + wave * 16 + cl;
    int na = min(arow, n - 1);
    const float4* x4 = (const float4*)x;
    float4 xr[8];
    #pragma unroll
    for (int kb = 0; kb < 4; ++kb) {
        int k0 = kb * 32 + kg * 8;
        xr[2 * kb]     = x4[(size_t)na * 32 + (k0 >> 2)];
        xr[2 * kb + 1] = x4[(size_t)na * 32 + (k0 >> 2) + 1];
    }
    f4 zero4 = {0.f, 0.f, 0.f, 0.f};
    f4 acc[4] = {zero4, zero4, zero4, zero4};
    #pragma unroll
    for (int kb = 0; kb < 4; ++kb) {
        int k0 = kb * 32 + kg * 8;
        float4 va = xr[2 * kb];
        float4 vb = xr[2 * kb + 1];
        h8 a;
        a[0] = (_Float16)va.x; a[1] = (_Float16)va.y; a[2] = (_Float16)va.z; a[3] = (_Float16)va.w;
        a[4] = (_Float16)vb.x; a[5] = (_Float16)vb.y; a[6] = (_Float16)vb.z; a[7] = (_Float16)vb.w;
        #pragma unroll
        for (int c = 0; c < 4; ++c) {
            h8 b = *(const h8*)&W1T[((c * 16 + cl) << 7) + k0];
            acc[c] = __builtin_amdgcn_mfma_f32_16x16x32_f16(a, b, acc[c], 0, 0, 0);
        }
    }
    int rbase = tile * 64 + wave * 16 + kg * 4;
    #pragma unroll
    for (int r = 0; r < 4; ++r) {
        int orow = rbase + r;
        if (orow < n) {
            #pragma unroll
            for (int c = 0; c < 4; ++c)
                out[(size_t)orow * 64 + c * 16 + cl] = __float2half((float)acc[c][r]);
        }
    }
}

// ---------------- fused: bin (blocks < nbin) + mm1 (blocks >= nbin) ----------------
struct SMemBin {
    u32 staged[BINCHUNK]; unsigned char stagedB[BINCHUNK];
    int lhist[256], lbase[256], gbase[256], lfill[256]; int wsum[4];
};

__global__ __launch_bounds__(256) void k_binmm(const int* __restrict__ src,
                                               const int* __restrict__ dst,
                                               int E, int n, int nbin,
                                               int* __restrict__ bucketFill,
                                               u32* __restrict__ binned,
                                               const float* __restrict__ x,
                                               const _Float16* __restrict__ W1T,
                                               __half* __restrict__ Ah) {
    __shared__ SMemBin sm;
    int bid = blockIdx.x, tid = threadIdx.x;
    if (bid < nbin) {
        int kbeg = bid * BINCHUNK;
        int cnt = min(BINCHUNK, E - kbeg);
        sm.lhist[tid] = 0; sm.lfill[tid] = 0;
        __syncthreads();
        for (int t = tid; t < cnt; t += 256)
            atomicAdd(&sm.lhist[dst[kbeg + t] >> NBITS], 1);
        __syncthreads();
        int v = sm.lhist[tid];
        int ex = excl_scan256(v, sm.wsum, tid);
        sm.lbase[tid] = ex;
        sm.gbase[tid] = v ? atomicAdd(&bucketFill[tid], v) : 0;
        __syncthreads();
        for (int t = tid; t < cnt; t += 256) {
            int d = dst[kbeg + t];
            int s = src[kbeg + t];
            int bk = d >> NBITS;
            int p = sm.lbase[bk] + atomicAdd(&sm.lfill[bk], 1);
            sm.staged[p] = ((u32)(d & (BSZ - 1)) << 23) | (u32)s;
            sm.stagedB[p] = (unsigned char)bk;
        }
        __syncthreads();
        for (int t = tid; t < cnt; t += 256) {
            int bk = sm.stagedB[t];
            binned[(size_t)bk * CAP + sm.gbase[bk] + (t - sm.lbase[bk])] = sm.staged[t];
        }
    } else {
        mm1_tile_mfma(bid - nbin, tid, n, x, W1T, Ah);
    }
}

// ---------------- per-bucket: degree, rowdesc, dinv, colidx; then pre-scale Ah rows by dinv ----------------
__global__ __launch_bounds__(512) void k_bucket(const u32* __restrict__ binned,
                                                const int* __restrict__ bucketFill,
                                                u32* __restrict__ rowdesc,
                                                float* __restrict__ dinvp,
                                                int* __restrict__ colidx,
                                                __half* __restrict__ Ah, int n) {
    __shared__ int cnt[BSZ];
    __shared__ int loff[BSZ];
    __shared__ float sdinv[BSZ];
    __shared__ int wsum[8];
    int b = blockIdx.x, tid = threadIdx.x;
    int ebeg = b * CAP;
    int fill = bucketFill[b];
    cnt[tid] = 0;
    __syncthreads();
    for (int e = tid; e < fill; e += 512)
        atomicAdd(&cnt[binned[ebeg + e] >> 23], 1);
    __syncthreads();
    int c0 = cnt[tid];
    int ex = excl_scan512(c0, wsum, tid);
    loff[tid] = ex;
    int node0 = (b << NBITS) + tid;
    float d0 = rsqrtf((float)c0 + 1.0f);
    sdinv[tid] = d0;
    if (node0 < n) {
        rowdesc[node0] = ((u32)(ebeg + ex) << 10) | (u32)min(c0, 1023);
        dinvp[node0] = d0;
    }
    __syncthreads();
    cnt[tid] = 0;
    __syncthreads();
    for (int e = tid; e < fill; e += 512) {
        u32 pv = binned[ebeg + e];
        int ln = pv >> 23;
        int pos = ebeg + loff[ln] + atomicAdd(&cnt[ln], 1);
        colidx[pos] = (int)(pv & 0x7FFFFF);
    }
    // pre-scale this bucket's Ah rows by dinv (so gather L1 is a plain row-sum)
    int nvalid = min(n - (b << NBITS), BSZ);
    uint4* rows = (uint4*)(Ah + ((size_t)b << NBITS) * 64);
    union U { uint4 u; __half2 h[4]; };
    for (int t = tid; t < nvalid * 8; t += 512) {
        float d = sdinv[t >> 3];
        U v; v.u = rows[t];
        #pragma unroll
        for (int q = 0; q < 4; ++q) {
            float2 f = __half22float2(v.h[q]);
            v.h[q] = __floats2half2_rn(f.x * d, f.y * d);
        }
        rows[t] = v.u;
    }
}

// ---------------- gather L1 ----------------
// 2 nodes per wave, 4 waves per block. 8 lanes per row (8 halves = 16 B/lane), 8 edge slots.
// hs rows PRE-SCALED by dinv -> plain row-sum; out = dinv * relu(dinv*S + b) (fp16, pre-scaled).
// Batch-0 AND batch-1 (edges 0..31) row loads for both nodes issued in the preload phase.
__global__ __launch_bounds__(256) void k_gather1(const __half* __restrict__ hs,
                                                 __half* __restrict__ out,
                                                 const u32* __restrict__ rowdesc,
                                                 const int* __restrict__ colidx,
                                                 const float* __restrict__ dinv,
                                                 const float* __restrict__ bias, int n) {
    int wid = threadIdx.x >> 6, lane = threadIdx.x & 63;
    int nbase = blockIdx.x * 8 + wid * 2;
    if (nbase >= n) return;
    int es = lane >> 3;          // edge slot 0..7
    int cc = lane & 7;           // channel chunk (8 halves = 16 B)
    const uint4* hs16 = (const uint4*)hs;
    union U { uint4 u; __half2 h[4]; };

    u32 rdv[2]; float div_[2]; U selfv[2]; int civ[2];
    #pragma unroll
    for (int i = 0; i < 2; ++i) {
        int node = min(nbase + i, n - 1);
        rdv[i] = rowdesc[node];
        div_[i] = dinv[node];
        selfv[i].u = hs16[((u32)node << 3) | cc];
    }
    #pragma unroll
    for (int i = 0; i < 2; ++i) {
        int beg = (int)(rdv[i] >> 10), deg = (int)(rdv[i] & 1023);
        civ[i] = (lane < deg) ? colidx[beg + lane] : n;    // n = zero pad row
    }
    U r0[2][2];
    #pragma unroll
    for (int i = 0; i < 2; ++i) {
        #pragma unroll
        for (int j = 0; j < 2; ++j) {
            int s = __shfl(civ[i], 8 * j + es);
            r0[i][j].u = hs16[((u32)s << 3) | cc];
        }
    }
    U r1[2][2];
    #pragma unroll
    for (int i = 0; i < 2; ++i) {
        int deg = (int)(rdv[i] & 1023);
        if (deg > 16) {                       // wave-uniform branch
            #pragma unroll
            for (int j = 0; j < 2; ++j) {
                int s = __shfl(civ[i], 8 * (j + 2) + es);
                r1[i][j].u = hs16[((u32)s << 3) | cc];
            }
        }
    }

    #pragma unroll
    for (int i = 0; i < 2; ++i) {
        int node = nbase + i;
        if (node >= n) break;                // wave-uniform
        int beg = (int)(rdv[i] >> 10);
        int deg = (int)(rdv[i] & 1023);
        int end = beg + deg;
        float a[8] = {0.f, 0.f, 0.f, 0.f, 0.f, 0.f, 0.f, 0.f};
        #pragma unroll
        for (int j = 0; j < 2; ++j) {
            #pragma unroll
            for (int q = 0; q < 4; ++q) {
                float2 f = __half22float2(r0[i][j].h[q]);
                a[2 * q] += f.x; a[2 * q + 1] += f.y;
            }
        }
        if (deg > 16) {
            #pragma unroll
            for (int j = 0; j < 2; ++j)
                #pragma unroll
                for (int q = 0; q < 4; ++q) {
                    float2 f = __half22float2(r1[i][j].h[q]);
                    a[2 * q] += f.x; a[2 * q + 1] += f.y;
                }
        }
        if (deg > 32) {
            U r[4];
            #pragma unroll
            for (int j = 0; j < 4; ++j) {
                int s = __shfl(civ[i], (8 * (j + 4) + es) & 63);
                r[j].u = hs16[((u32)s << 3) | cc];
            }
            #pragma unroll
            for (int j = 0; j < 4; ++j)
                #pragma unroll
                for (int q = 0; q < 4; ++q) {
                    float2 f = __half22float2(r[j].h[q]);
                    a[2 * q] += f.x; a[2 * q + 1] += f.y;
                }
        }
        for (int e = beg + 64 + es; e < end; e += 8) {
            int s = colidx[e];
            U r; r.u = hs16[((u32)s << 3) | cc];
            #pragma unroll
            for (int q = 0; q < 4; ++q) {
                float2 f = __half22float2(r.h[q]);
                a[2 * q] += f.x; a[2 * q + 1] += f.y;
            }
        }
        #pragma unroll
        for (int q = 0; q < 8; ++q) {
            a[q] += __shfl_xor(a[q], 8);
            a[q] += __shfl_xor(a[q], 16);
            a[q] += __shfl_xor(a[q], 32);
        }

        if (lane < 8) {
            float di = div_[i];
            #pragma unroll
            for (int q = 0; q < 4; ++q) {
                float2 f = __half22float2(selfv[i].h[q]);
                a[2 * q] += f.x; a[2 * q + 1] += f.y;
            }
            float4 b0 = ((const float4*)bias)[2 * cc];
            float4 b1 = ((const float4*)bias)[2 * cc + 1];
            float v[8];
            v[0] = fmaxf(di * a[0] + b0.x, 0.f) * di;
            v[1] = fmaxf(di * a[1] + b0.y, 0.f) * di;
            v[2] = fmaxf(di * a[2] + b0.z, 0.f) * di;
            v[3] = fmaxf(di * a[3] + b0.w, 0.f) * di;
            v[4] = fmaxf(di * a[4] + b1.x, 0.f) * di;
            v[5] = fmaxf(di * a[5] + b1.y, 0.f) * di;
            v[6] = fmaxf(di * a[6] + b1.z, 0.f) * di;
            v[7] = fmaxf(di * a[7] + b1.w, 0.f) * di;
            U o;
            o.h[0] = __floats2half2_rn(v[0], v[1]);
            o.h[1] = __floats2half2_rn(v[2], v[3]);
            o.h[2] = __floats2half2_rn(v[4], v[5]);
            o.h[3] = __floats2half2_rn(v[6], v[7]);
            ((uint4*)out)[((u32)node << 3) | cc] = o.u;
        }
    }
}

// ---------------- fused gather-L2 + mm2 ----------------
// One block = 64 nodes (the mm2 MFMA tile). 4 waves; wave w owns rows w*16..w*16+15,
// produced in 8 iterations of the 2-node gather pipeline, staged in LDS (fp16),
// then consumed as the MFMA A-fragments of the SAME wave (no __syncthreads needed).
// out = [ g @ Wmu + bmu | g @ Wls + bls ], g = dinv * (row-sum + self).
__global__ __launch_bounds__(256) void k_gmm2(const __half* __restrict__ hs,
                                              const u32* __restrict__ rowdesc,
                                              const int* __restrict__ colidx,
                                              const float* __restrict__ dinv,
                                              const _Float16* __restrict__ WT2,
                                              const float* __restrict__ bmu,
                                              const float* __restrict__ bls,
                                              float* __restrict__ out, int n) {
    __shared__ _Float16 sg[64][72];   // 144 B row stride: 16B-aligned, 8-bank cycle (2-way, free)
    int wid = threadIdx.x >> 6, lane = threadIdx.x & 63;
    int tile = blockIdx.x;
    int es = lane >> 3;          // edge slot 0..7
    int cc = lane & 7;           // channel chunk (8 halves = 16 B)
    const uint4* hs16 = (const uint4*)hs;
    union U { uint4 u; __half2 h[4]; };

    // ---- gather phase: 8 iterations x 2 nodes per wave ----
    for (int it = 0; it < 8; ++it) {
        int nbase = tile * 64 + wid * 16 + it * 2;
        if (nbase >= n) continue;            // wave-uniform
        u32 rdv[2]; float div_[2]; U selfv[2]; int civ[2];
        #pragma unroll
        for (int i = 0; i < 2; ++i) {
            int node = min(nbase + i, n - 1);
            rdv[i] = rowdesc[node];
            div_[i] = dinv[node];
            selfv[i].u = hs16[((u32)node << 3) | cc];
        }
        #pragma unroll
        for (int i = 0; i < 2; ++i) {
            int beg = (int)(rdv[i] >> 10), deg = (int)(rdv[i] & 1023);
            civ[i] = (lane < deg) ? colidx[beg + lane] : n;    // n = zero pad row
        }
        U r0[2][2];
        #pragma unroll
        for (int i = 0; i < 2; ++i) {
            #pragma unroll
            for (int j = 0; j < 2; ++j) {
                int s = __shfl(civ[i], 8 * j + es);
                r0[i][j].u = hs16[((u32)s << 3) | cc];
            }
        }
        U r1[2][2];
        #pragma unroll
        for (int i = 0; i < 2; ++i) {
            int deg = (int)(rdv[i] & 1023);
            if (deg > 16) {                   // wave-uniform branch
                #pragma unroll
                for (int j = 0; j < 2; ++j) {
                    int s = __shfl(civ[i], 8 * (j + 2) + es);
                    r1[i][j].u = hs16[((u32)s << 3) | cc];
                }
            }
        }
        #pragma unroll
        for (int i = 0; i < 2; ++i) {
            int node = nbase + i;
            if (node >= n) break;            // wave-uniform
            int beg = (int)(rdv[i] >> 10);
            int deg = (int)(rdv[i] & 1023);
            int end = beg + deg;
            float a[8] = {0.f, 0.f, 0.f, 0.f, 0.f, 0.f, 0.f, 0.f};
            #pragma unroll
            for (int j = 0; j < 2; ++j) {
                #pragma unroll
                for (int q = 0; q < 4; ++q) {
                    float2 f = __half22float2(r0[i][j].h[q]);
                    a[2 * q] += f.x; a[2 * q + 1] += f.y;
                }
            }
            if (deg > 16) {
                #pragma unroll
                for (int j = 0; j < 2; ++j)
                    #pragma unroll
                    for (int q = 0; q < 4; ++q) {
                        float2 f = __half22float2(r1[i][j].h[q]);
                        a[2 * q] += f.x; a[2 * q + 1] += f.y;
                    }
            }
            if (deg > 32) {
                U r[4];
                #pragma unroll
                for (int j = 0; j < 4; ++j) {
                    int s = __shfl(civ[i], (8 * (j + 4) + es) & 63);
                    r[j].u = hs16[((u32)s << 3) | cc];
                }
                #pragma unroll
                for (int j = 0; j < 4; ++j)
                    #pragma unroll
                    for (int q = 0; q < 4; ++q) {
                        float2 f = __half22float2(r[j].h[q]);
                        a[2 * q] += f.x; a[2 * q + 1] += f.y;
                    }
            }
            for (int e = beg + 64 + es; e < end; e += 8) {
                int s = colidx[e];
                U r; r.u = hs16[((u32)s << 3) | cc];
                #pragma unroll
                for (int q = 0; q < 4; ++q) {
                    float2 f = __half22float2(r.h[q]);
                    a[2 * q] += f.x; a[2 * q + 1] += f.y;
                }
            }
            #pragma unroll
            for (int q = 0; q < 8; ++q) {
                a[q] += __shfl_xor(a[q], 8);
                a[q] += __shfl_xor(a[q], 16);
                a[q] += __shfl_xor(a[q], 32);
            }
            if (lane < 8) {
                float di = div_[i];
                #pragma unroll
                for (int q = 0; q < 4; ++q) {
                    float2 f = __half22float2(selfv[i].h[q]);
                    a[2 * q] += f.x; a[2 * q + 1] += f.y;
                }
                U o;
                o.h[0] = __floats2half2_rn(di * a[0], di * a[1]);
                o.h[1] = __floats2half2_rn(di * a[2], di * a[3]);
                o.h[2] = __floats2half2_rn(di * a[4], di * a[5]);
                o.h[3] = __floats2half2_rn(di * a[6], di * a[7]);
                *(uint4*)&sg[wid * 16 + it * 2 + i][cc * 8] = o.u;
            }
        }
    }

    // ---- mm2 phase: A-fragments from this wave's own LDS rows ----
    // (producer lanes and consumer lanes are in the same wave; compiler-inserted
    //  lgkmcnt waits order the ds_write -> ds_read dependency.)
    int cl = lane & 15, kg = lane >> 4;
    f4 zero4 = {0.f, 0.f, 0.f, 0.f};
    f4 acc[4] = {zero4, zero4, zero4, zero4};
    #pragma unroll
    for (int kb = 0; kb < 2; ++kb) {
        int k0 = kb * 32 + kg * 8;
        h8 a = *(const h8*)&sg[wid * 16 + cl][k0];
        #pragma unroll
        for (int c = 0; c < 4; ++c) {
            h8 b = *(const h8*)&WT2[((c * 16 + cl) << 6) + k0];
            acc[c] = __builtin_amdgcn_mfma_f32_16x16x32_f16(a, b, acc[c], 0, 0, 0);
        }
    }
    int rbase = tile * 64 + wid * 16 + kg * 4;
    #pragma unroll
    for (int c = 0; c < 4; ++c) {
        int col = c * 16 + cl;
        float bv = (col < 32) ? bmu[col] : bls[col - 32];
        float* obase = (col < 32) ? (out + col) : (out + (size_t)n * 32 + (col - 32));
        #pragma unroll
        for (int r = 0; r < 4; ++r) {
            int orow = rbase + r;
            if (orow < n) obase[(size_t)orow * 32] = (float)acc[c][r] + bv;
        }
    }
}

// ---------------- launcher ----------------

extern "C" void kernel_launch(void* const* d_in, const int* in_sizes, int n_in,
                              void* d_out, int out_size, void* d_ws, size_t ws_size,
                              hipStream_t stream) {
    const float* x   = (const float*)d_in[0];
    const int*   ei  = (const int*)d_in[1];
    const float* W1  = (const float*)d_in[2];
    const float* b1  = (const float*)d_in[3];
    const float* Wmu = (const float*)d_in[4];
    const float* bmu = (const float*)d_in[5];
    const float* Wls = (const float*)d_in[6];
    const float* bls = (const float*)d_in[7];
    float* out = (float*)d_out;

    int n = in_sizes[0] / IN_C;   // 100000
    int E = in_sizes[1] / 2;      // 1600000
    const int* srcp = ei;
    const int* dstp = ei + E;
    int NBUK = (n + BSZ - 1) >> NBITS;            // 196
    int nbin = (E + BINCHUNK - 1) / BINCHUNK;     // 391
    int ntiles = (n + 63) / 64;                   // 1563

    char* p = (char*)d_ws;
    __half* Ah  = (__half*)p; p += (size_t)(n + 1) * H * sizeof(__half);
    __half* Bh  = (__half*)p; p += (size_t)(n + 1) * H * sizeof(__half);
    float* dinv = (float*)p;  p += (size_t)n * sizeof(float);
    u32* rowdesc = (u32*)p;   p += (size_t)n * sizeof(u32);
    int* colidx = (int*)p;    p += (size_t)NBUK * CAP * sizeof(int);
    u32* binned = (u32*)p;    p += (size_t)NBUK * CAP * sizeof(u32);
    int* bucketFill = (int*)p; p += 256 * sizeof(int);
    _Float16* W1T = (_Float16*)p; p += 64 * 128 * sizeof(_Float16);
    _Float16* WT2 = (_Float16*)p; p += 64 * 64 * sizeof(_Float16);

    k_init<<<16, 256, 0, stream>>>(bucketFill, Ah + (size_t)n * H, Bh + (size_t)n * H,
                                   W1, Wmu, Wls, W1T, WT2);
    k_binmm<<<nbin + ntiles, 256, 0, stream>>>(srcp, dstp, E, n, nbin,
                                               bucketFill, binned, x, W1T, Ah);
    k_bucket<<<NBUK, 512, 0, stream>>>(binned, bucketFill, rowdesc, dinv, colidx, Ah, n);

    k_gather1<<<(n + 7) / 8, 256, 0, stream>>>(Ah, Bh, rowdesc, colidx, dinv, b1, n);
    k_gmm2<<<ntiles, 256, 0, stream>>>(Bh, rowdesc, colidx, dinv, WT2, bmu, bls, out, n);
}

// Round 11
// 231.209 us; speedup vs baseline: 1.0152x; 1.0152x over previous
//
#include <hip/hip_runtime.h>
#include <hip/hip_fp16.h>

#define IN_C 128
#define H 64
#define NBITS 9            // 512 nodes per bucket
#define BSZ 512
#define CAP 16384          // edge capacity per bucket (mean 8192, sigma ~90)
#define LDSCAP 12288       // LDS staging slots per bucket (mean + 45 sigma)
#define BINCHUNK 4096      // edges per bin block

typedef unsigned int u32;
typedef __attribute__((ext_vector_type(8))) _Float16 h8;
typedef __attribute__((ext_vector_type(4))) float f4;

// exclusive prefix sum of v across 256 threads; wsum = 4-int LDS scratch
__device__ __forceinline__ int excl_scan256(int v, int* wsum, int tid) {
    int lane = tid & 63, wid = tid >> 6;
    int s = v;
    #pragma unroll
    for (int off = 1; off < 64; off <<= 1) {
        int t = __shfl_up(s, off);
        if (lane >= off) s += t;
    }
    if (lane == 63) wsum[wid] = s;
    __syncthreads();
    if (tid == 0) {
        int c = 0;
        #pragma unroll
        for (int i = 0; i < 4; ++i) { int t = wsum[i]; wsum[i] = c; c += t; }
    }
    __syncthreads();
    return s - v + wsum[wid];
}

// exclusive prefix sum across 512 threads; wsum = 8-int LDS scratch
__device__ __forceinline__ int excl_scan512(int v, int* wsum, int tid) {
    int lane = tid & 63, wid = tid >> 6;
    int s = v;
    #pragma unroll
    for (int off = 1; off < 64; off <<= 1) {
        int t = __shfl_up(s, off);
        if (lane >= off) s += t;
    }
    if (lane == 63) wsum[wid] = s;
    __syncthreads();
    if (tid == 0) {
        int c = 0;
        #pragma unroll
        for (int i = 0; i < 8; ++i) { int t = wsum[i]; wsum[i] = c; c += t; }
    }
    __syncthreads();
    return s - v + wsum[wid];
}

// ---------------- init: zero bucketFill + pad rows + build fp16 transposed weights ----------------
__global__ __launch_bounds__(256) void k_init(int* __restrict__ bucketFill,
                                              __half* __restrict__ z0,
                                              __half* __restrict__ z1,
                                              const float* __restrict__ W1,
                                              const float* __restrict__ Wmu,
                                              const float* __restrict__ Wls,
                                              _Float16* __restrict__ W1T,
                                              _Float16* __restrict__ WT2) {
    int tid = threadIdx.x;
    int gt = blockIdx.x * 256 + tid;
    if (blockIdx.x == 0) {
        bucketFill[tid] = 0;
        if (tid < H) { z0[tid] = __float2half(0.f); z1[tid] = __float2half(0.f); }
    }
    for (int t = gt; t < 64 * 128; t += gridDim.x * 256) {
        int col = t >> 7, k = t & 127;
        W1T[t] = (_Float16)W1[k * 64 + col];
    }
    for (int t = gt; t < 64 * 64; t += gridDim.x * 256) {
        int col = t >> 6, k = t & 63;
        WT2[t] = (_Float16)((col < 32) ? Wmu[k * 32 + col] : Wls[k * 32 + (col - 32)]);
    }
}

// ---------------- mm1 tile (MFMA): Ah[node][c] = fp16( x[node][:] @ W1[:][c] ), UNSCALED
// All 8 x-loads (128 B/lane) issued up front.
__device__ __forceinline__ void mm1_tile_mfma(int tile, int t256, int n,
                                              const float* __restrict__ x,
                                              const _Float16* __restrict__ W1T,
                                              __half* __restrict__ out) {
    int wave = t256 >> 6, lane = t256 & 63;
    int cl = lane & 15;
    int kg = lane >> 4;
    int arow = tile * 64 + wave * 16 + cl;
    int na = min(arow, n - 1);
    const float4* x4 = (const float4*)x;
    float4 xr[8];
    #pragma unroll
    for (int kb = 0; kb < 4; ++kb) {
        int k0 = kb * 32 + kg * 8;
        xr[2 * kb]     = x4[(size_t)na * 32 + (k0 >> 2)];
        xr[2 * kb + 1] = x4[(size_t)na * 32 + (k0 >> 2) + 1];
    }
    f4 zero4 = {0.f, 0.f, 0.f, 0.f};
    f4 acc[4] = {zero4, zero4, zero4, zero4};
    #pragma unroll
    for (int kb = 0; kb < 4; ++kb) {
        int k0 = kb * 32 + kg * 8;
        float4 va = xr[2 * kb];
        float4 vb = xr[2 * kb + 1];
        h8 a;
        a[0] = (_Float16)va.x; a[1] = (_Float16)va.y; a[2] = (_Float16)va.z; a[3] = (_Float16)va.w;
        a[4] = (_Float16)vb.x; a[5] = (_Float16)vb.y; a[6] = (_Float16)vb.z; a[7] = (_Float16)vb.w;
        #pragma unroll
        for (int c = 0; c < 4; ++c) {
            h8 b = *(const h8*)&W1T[((c * 16 + cl) << 7) + k0];
            acc[c] = __builtin_amdgcn_mfma_f32_16x16x32_f16(a, b, acc[c], 0, 0, 0);
        }
    }
    int rbase = tile * 64 + wave * 16 + kg * 4;
    #pragma unroll
    for (int r = 0; r < 4; ++r) {
        int orow = rbase + r;
        if (orow < n) {
            #pragma unroll
            for (int c = 0; c < 4; ++c)
                out[(size_t)orow * 64 + c * 16 + cl] = __float2half((float)acc[c][r]);
        }
    }
}

// ---------------- fused: bin (blocks < nbin) + mm1 (blocks >= nbin) ----------------
struct SMemBin {
    u32 staged[BINCHUNK]; unsigned char stagedB[BINCHUNK];
    int lhist[256], lbase[256], gbase[256], lfill[256]; int wsum[4];
};

__global__ __launch_bounds__(256) void k_binmm(const int* __restrict__ src,
                                               const int* __restrict__ dst,
                                               int E, int n, int nbin,
                                               int* __restrict__ bucketFill,
                                               u32* __restrict__ binned,
                                               const float* __restrict__ x,
                                               const _Float16* __restrict__ W1T,
                                               __half* __restrict__ Ah) {
    __shared__ SMemBin sm;
    int bid = blockIdx.x, tid = threadIdx.x;
    if (bid < nbin) {
        int kbeg = bid * BINCHUNK;
        int cnt = min(BINCHUNK, E - kbeg);
        sm.lhist[tid] = 0; sm.lfill[tid] = 0;
        __syncthreads();
        for (int t = tid; t < cnt; t += 256)
            atomicAdd(&sm.lhist[dst[kbeg + t] >> NBITS], 1);
        __syncthreads();
        int v = sm.lhist[tid];
        int ex = excl_scan256(v, sm.wsum, tid);
        sm.lbase[tid] = ex;
        sm.gbase[tid] = v ? atomicAdd(&bucketFill[tid], v) : 0;
        __syncthreads();
        for (int t = tid; t < cnt; t += 256) {
            int d = dst[kbeg + t];
            int s = src[kbeg + t];
            int bk = d >> NBITS;
            int p = sm.lbase[bk] + atomicAdd(&sm.lfill[bk], 1);
            sm.staged[p] = ((u32)(d & (BSZ - 1)) << 23) | (u32)s;
            sm.stagedB[p] = (unsigned char)bk;
        }
        __syncthreads();
        for (int t = tid; t < cnt; t += 256) {
            int bk = sm.stagedB[t];
            binned[(size_t)bk * CAP + sm.gbase[bk] + (t - sm.lbase[bk])] = sm.staged[t];
        }
    } else {
        mm1_tile_mfma(bid - nbin, tid, n, x, W1T, Ah);
    }
}

// ---------------- per-bucket: degree, rowdesc, dinv, colidx; then pre-scale Ah rows by dinv ----------------
// binned is read from global ONCE (staged into LDS; fill = 8192 +/- 90, LDSCAP = mean + 45 sigma).
// Only 196 blocks on 256 CUs -> 55 KB LDS costs no occupancy (grid-limited to 1 block/CU).
__global__ __launch_bounds__(512) void k_bucket(const u32* __restrict__ binned,
                                                const int* __restrict__ bucketFill,
                                                u32* __restrict__ rowdesc,
                                                float* __restrict__ dinvp,
                                                int* __restrict__ colidx,
                                                __half* __restrict__ Ah, int n) {
    __shared__ u32 sE[LDSCAP];
    __shared__ int cnt[BSZ];
    __shared__ int loff[BSZ];
    __shared__ float sdinv[BSZ];
    __shared__ int wsum[8];
    int b = blockIdx.x, tid = threadIdx.x;
    int ebeg = b * CAP;
    int fill = min(bucketFill[b], LDSCAP);
    cnt[tid] = 0;
    __syncthreads();
    // single global pass: stage + histogram
    for (int e = tid; e < fill; e += 512) {
        u32 pv = binned[ebeg + e];
        sE[e] = pv;
        atomicAdd(&cnt[pv >> 23], 1);
    }
    __syncthreads();
    int c0 = cnt[tid];
    int ex = excl_scan512(c0, wsum, tid);
    loff[tid] = ex;
    int node0 = (b << NBITS) + tid;
    float d0 = rsqrtf((float)c0 + 1.0f);
    sdinv[tid] = d0;
    if (node0 < n) {
        rowdesc[node0] = ((u32)(ebeg + ex) << 10) | (u32)min(c0, 1023);
        dinvp[node0] = d0;
    }
    __syncthreads();
    cnt[tid] = 0;
    __syncthreads();
    // scatter from LDS
    for (int e = tid; e < fill; e += 512) {
        u32 pv = sE[e];
        int ln = pv >> 23;
        int pos = ebeg + loff[ln] + atomicAdd(&cnt[ln], 1);
        colidx[pos] = (int)(pv & 0x7FFFFF);
    }
    // pre-scale this bucket's Ah rows by dinv (so gather L1 is a plain row-sum)
    int nvalid = min(n - (b << NBITS), BSZ);
    uint4* rows = (uint4*)(Ah + ((size_t)b << NBITS) * 64);
    union U { uint4 u; __half2 h[4]; };
    for (int t = tid; t < nvalid * 8; t += 512) {
        float d = sdinv[t >> 3];
        U v; v.u = rows[t];
        #pragma unroll
        for (int q = 0; q < 4; ++q) {
            float2 f = __half22float2(v.h[q]);
            v.h[q] = __floats2half2_rn(f.x * d, f.y * d);
        }
        rows[t] = v.u;
    }
}

// ---------------- gather ----------------
// 2 nodes per wave, 4 waves per block. 8 lanes per row (8 halves = 16 B/lane), 8 edge slots.
// hs rows are PRE-SCALED by dinv (both layers) -> plain row-sum, then:
//   L1: out = dinv * relu(dinv*S + b)   (fp16, pre-scaled for L2)
//   L2: out = dinv * S                  (fp16 for MFMA mm2)
// Batch-0 AND batch-1 (edges 0..31) row loads for both nodes issued in the preload
// phase (deg>16 condition is wave-uniform) -> their latency hides under accumulation.
template <bool L1, typename OutT>
__global__ __launch_bounds__(256) void k_gather(const __half* __restrict__ hs,
                                                OutT* __restrict__ out,
                                                const u32* __restrict__ rowdesc,
                                                const int* __restrict__ colidx,
                                                const float* __restrict__ dinv,
                                                const float* __restrict__ bias, int n) {
    int wid = threadIdx.x >> 6, lane = threadIdx.x & 63;
    int nbase = blockIdx.x * 8 + wid * 2;
    if (nbase >= n) return;
    int es = lane >> 3;          // edge slot 0..7
    int cc = lane & 7;           // channel chunk (8 halves = 16 B)
    const uint4* hs16 = (const uint4*)hs;
    union U { uint4 u; __half2 h[4]; };

    // ---- preload: descriptors, self rows, colidx, edges 0..31 of both nodes ----
    u32 rdv[2]; float div_[2]; U selfv[2]; int civ[2];
    #pragma unroll
    for (int i = 0; i < 2; ++i) {
        int node = min(nbase + i, n - 1);
        rdv[i] = rowdesc[node];
        div_[i] = dinv[node];
        selfv[i].u = hs16[((u32)node << 3) | cc];
    }
    #pragma unroll
    for (int i = 0; i < 2; ++i) {
        int beg = (int)(rdv[i] >> 10), deg = (int)(rdv[i] & 1023);
        civ[i] = (lane < deg) ? colidx[beg + lane] : n;    // n = zero pad row
    }
    U r0[2][2];
    #pragma unroll
    for (int i = 0; i < 2; ++i) {
        #pragma unroll
        for (int j = 0; j < 2; ++j) {
            int s = __shfl(civ[i], 8 * j + es);
            r0[i][j].u = hs16[((u32)s << 3) | cc];
        }
    }
    U r1[2][2];
    #pragma unroll
    for (int i = 0; i < 2; ++i) {
        int deg = (int)(rdv[i] & 1023);
        if (deg > 16) {                       // wave-uniform branch
            #pragma unroll
            for (int j = 0; j < 2; ++j) {
                int s = __shfl(civ[i], 8 * (j + 2) + es);
                r1[i][j].u = hs16[((u32)s << 3) | cc];
            }
        }
    }

    // ---- per-node finish ----
    #pragma unroll
    for (int i = 0; i < 2; ++i) {
        int node = nbase + i;
        if (node >= n) break;                // wave-uniform
        int beg = (int)(rdv[i] >> 10);
        int deg = (int)(rdv[i] & 1023);
        int end = beg + deg;
        float a[8] = {0.f, 0.f, 0.f, 0.f, 0.f, 0.f, 0.f, 0.f};
        #pragma unroll
        for (int j = 0; j < 2; ++j) {        // edges 0..15 (preloaded)
            #pragma unroll
            for (int q = 0; q < 4; ++q) {
                float2 f = __half22float2(r0[i][j].h[q]);
                a[2 * q] += f.x; a[2 * q + 1] += f.y;
            }
        }
        if (deg > 16) {                      // edges 16..31 (preloaded)
            #pragma unroll
            for (int j = 0; j < 2; ++j)
                #pragma unroll
                for (int q = 0; q < 4; ++q) {
                    float2 f = __half22float2(r1[i][j].h[q]);
                    a[2 * q] += f.x; a[2 * q + 1] += f.y;
                }
        }
        if (deg > 32) {                      // edges 32..63 (rare)
            U r[4];
            #pragma unroll
            for (int j = 0; j < 4; ++j) {
                int s = __shfl(civ[i], (8 * (j + 4) + es) & 63);
                r[j].u = hs16[((u32)s << 3) | cc];
            }
            #pragma unroll
            for (int j = 0; j < 4; ++j)
                #pragma unroll
                for (int q = 0; q < 4; ++q) {
                    float2 f = __half22float2(r[j].h[q]);
                    a[2 * q] += f.x; a[2 * q + 1] += f.y;
                }
        }
        for (int e = beg + 64 + es; e < end; e += 8) {   // deg > 64 tail (very rare)
            int s = colidx[e];
            U r; r.u = hs16[((u32)s << 3) | cc];
            #pragma unroll
            for (int q = 0; q < 4; ++q) {
                float2 f = __half22float2(r.h[q]);
                a[2 * q] += f.x; a[2 * q + 1] += f.y;
            }
        }
        // reduce over the 8 edge slots
        #pragma unroll
        for (int q = 0; q < 8; ++q) {
            a[q] += __shfl_xor(a[q], 8);
            a[q] += __shfl_xor(a[q], 16);
            a[q] += __shfl_xor(a[q], 32);
        }

        if (lane < 8) {
            float di = div_[i];
            #pragma unroll
            for (int q = 0; q < 4; ++q) {    // self row (pre-scaled)
                float2 f = __half22float2(selfv[i].h[q]);
                a[2 * q] += f.x; a[2 * q + 1] += f.y;
            }
            float v[8];
            #pragma unroll
            for (int q = 0; q < 8; ++q) v[q] = di * a[q];
            if (L1) {
                float4 b0 = ((const float4*)bias)[2 * cc];
                float4 b1 = ((const float4*)bias)[2 * cc + 1];
                v[0] = fmaxf(v[0] + b0.x, 0.f) * di;
                v[1] = fmaxf(v[1] + b0.y, 0.f) * di;
                v[2] = fmaxf(v[2] + b0.z, 0.f) * di;
                v[3] = fmaxf(v[3] + b0.w, 0.f) * di;
                v[4] = fmaxf(v[4] + b1.x, 0.f) * di;
                v[5] = fmaxf(v[5] + b1.y, 0.f) * di;
                v[6] = fmaxf(v[6] + b1.z, 0.f) * di;
                v[7] = fmaxf(v[7] + b1.w, 0.f) * di;
            }
            if constexpr (sizeof(OutT) == 2) {
                U o;
                o.h[0] = __floats2half2_rn(v[0], v[1]);
                o.h[1] = __floats2half2_rn(v[2], v[3]);
                o.h[2] = __floats2half2_rn(v[4], v[5]);
                o.h[3] = __floats2half2_rn(v[6], v[7]);
                ((uint4*)out)[((u32)node << 3) | cc] = o.u;
            } else {
                ((float4*)out)[((u32)node << 4) | (2 * cc)]     = make_float4(v[0], v[1], v[2], v[3]);
                ((float4*)out)[((u32)node << 4) | (2 * cc + 1)] = make_float4(v[4], v[5], v[6], v[7]);
            }
        }
    }
}

// ---------------- mm2 (MFMA): out = [ G @ Wmu + bmu | G @ Wls + bls ]
__global__ __launch_bounds__(256) void k_mm2(const __half* __restrict__ G,
                                             const _Float16* __restrict__ WT2,
                                             const float* __restrict__ bmu,
                                             const float* __restrict__ bls,
                                             float* __restrict__ out, int n) {
    int tile = blockIdx.x;
    int wave = threadIdx.x >> 6, lane = threadIdx.x & 63;
    int cl = lane & 15, kg = lane >> 4;
    int arow = tile * 64 + wave * 16 + cl;
    int na = min(arow, n - 1);
    const _Float16* Gf = (const _Float16*)G;
    f4 zero4 = {0.f, 0.f, 0.f, 0.f};
    f4 acc[4] = {zero4, zero4, zero4, zero4};
    #pragma unroll
    for (int kb = 0; kb < 2; ++kb) {
        int k0 = kb * 32 + kg * 8;
        h8 a = *(const h8*)&Gf[((size_t)na << 6) + k0];
        #pragma unroll
        for (int c = 0; c < 4; ++c) {
            h8 b = *(const h8*)&WT2[((c * 16 + cl) << 6) + k0];
            acc[c] = __builtin_amdgcn_mfma_f32_16x16x32_f16(a, b, acc[c], 0, 0, 0);
        }
    }
    int rbase = tile * 64 + wave * 16 + kg * 4;
    #pragma unroll
    for (int c = 0; c < 4; ++c) {
        int col = c * 16 + cl;
        float bv = (col < 32) ? bmu[col] : bls[col - 32];
        float* obase = (col < 32) ? (out + col) : (out + (size_t)n * 32 + (col - 32));
        #pragma unroll
        for (int r = 0; r < 4; ++r) {
            int orow = rbase + r;
            if (orow < n) obase[(size_t)orow * 32] = (float)acc[c][r] + bv;
        }
    }
}

// ---------------- launcher ----------------

extern "C" void kernel_launch(void* const* d_in, const int* in_sizes, int n_in,
                              void* d_out, int out_size, void* d_ws, size_t ws_size,
                              hipStream_t stream) {
    const float* x   = (const float*)d_in[0];
    const int*   ei  = (const int*)d_in[1];
    const float* W1  = (const float*)d_in[2];
    const float* b1  = (const float*)d_in[3];
    const float* Wmu = (const float*)d_in[4];
    const float* bmu = (const float*)d_in[5];
    const float* Wls = (const float*)d_in[6];
    const float* bls = (const float*)d_in[7];
    float* out = (float*)d_out;

    int n = in_sizes[0] / IN_C;   // 100000
    int E = in_sizes[1] / 2;      // 1600000
    const int* srcp = ei;
    const int* dstp = ei + E;
    int NBUK = (n + BSZ - 1) >> NBITS;            // 196
    int nbin = (E + BINCHUNK - 1) / BINCHUNK;     // 391
    int ntiles = (n + 63) / 64;                   // 1563

    char* p = (char*)d_ws;
    __half* Ah  = (__half*)p; p += (size_t)(n + 1) * H * sizeof(__half);
    __half* Bh  = (__half*)p; p += (size_t)(n + 1) * H * sizeof(__half);
    __half* G   = (__half*)p; p += (size_t)n * H * sizeof(__half);
    float* dinv = (float*)p;  p += (size_t)n * sizeof(float);
    u32* rowdesc = (u32*)p;   p += (size_t)n * sizeof(u32);
    int* colidx = (int*)p;    p += (size_t)NBUK * CAP * sizeof(int);
    u32* binned = (u32*)p;    p += (size_t)NBUK * CAP * sizeof(u32);
    int* bucketFill = (int*)p; p += 256 * sizeof(int);
    _Float16* W1T = (_Float16*)p; p += 64 * 128 * sizeof(_Float16);
    _Float16* WT2 = (_Float16*)p; p += 64 * 64 * sizeof(_Float16);

    k_init<<<16, 256, 0, stream>>>(bucketFill, Ah + (size_t)n * H, Bh + (size_t)n * H,
                                   W1, Wmu, Wls, W1T, WT2);
    k_binmm<<<nbin + ntiles, 256, 0, stream>>>(srcp, dstp, E, n, nbin,
                                               bucketFill, binned, x, W1T, Ah);
    k_bucket<<<NBUK, 512, 0, stream>>>(binned, bucketFill, rowdesc, dinv, colidx, Ah, n);

    k_gather<true, __half><<<(n + 7) / 8, 256, 0, stream>>>(Ah, Bh, rowdesc, colidx, dinv, b1, n);
    k_gather<false, __half><<<(n + 7) / 8, 256, 0, stream>>>(Bh, G, rowdesc, colidx, dinv, nullptr, n);
    k_mm2<<<(n + 63) / 64, 256, 0, stream>>>(G, WT2, bmu, bls, out, n);
}